// Round 12
// baseline (72.362 us; speedup 1.0000x reference)
//
#include <hip/hip_runtime.h>
#include <hip/hip_bf16.h>

// GraphSAGE 2-layer forward, SPLIT topology (round-11) with LDS-staged GEMM:
//   k_wprep: Wt = [Wx1|Wn1] cols, bf16 hi/lo
//   k_gath:  one wave per sample row: gather f1 + mean10(f2) -> A0/A1 bf16
//   k_gemm:  h1 = relu([A0@Wx1 ; A1@Wn1] + b); block = 64-row strip x branch;
//            A staged ONCE in LDS (32KB, XOR swizzle); W frags in registers.
//            LAUNCHED TWICE (idempotent) as a timing probe: round delta vs
//            round 11 isolates gemm-vs-gather cost attribution.
//   k_out:   per output row: h0, g0, normalize, FC

typedef __bf16 bf16x8 __attribute__((ext_vector_type(8)));
typedef __bf16 bf16x4 __attribute__((ext_vector_type(4)));
typedef float  f32x4  __attribute__((ext_vector_type(4)));

constexpr int IN    = 256;
constexpr int HIDC  = 128;
constexpr int ROWS1 = 512 * 25;   // 12800

// ---------------- Kernel P0: Wt = [Wx1|Wn1] columns as bf16 hi/lo -----------
__global__ __launch_bounds__(256) void k_wprep(
    const float* __restrict__ Wx, const float* __restrict__ Wn,
    __bf16* __restrict__ WtH, __bf16* __restrict__ WtL)
{
    const int j = blockIdx.x;
    const int k = threadIdx.x;
    const float v = (j < HIDC) ? Wx[(size_t)k * HIDC + j]
                               : Wn[(size_t)k * HIDC + (j - HIDC)];
    const __bf16 h = (__bf16)v;
    const __bf16 l = (__bf16)(v - (float)h);
    const size_t o = (size_t)j * IN + k;
    WtH[o] = h;
    WtL[o] = l;
}

// ---------------- Kernel G: gather f1 + mean10(f2) -> bf16 panels -----------
__global__ __launch_bounds__(512) void k_gath(
    const int* __restrict__ ids1, const int* __restrict__ ids2,
    const float* __restrict__ feats,
    __bf16* __restrict__ A0, __bf16* __restrict__ A1)
{
    const int r    = blockIdx.x * 8 + (threadIdx.x >> 6);
    const int lane = threadIdx.x & 63;
    const int base = r * 10;

    const float4 vx = ((const float4*)(feats + (size_t)ids1[r] * IN))[lane];
    float4 s = make_float4(0.f, 0.f, 0.f, 0.f);
    #pragma unroll
    for (int kk = 0; kk < 10; ++kk) {
        const float4 v = ((const float4*)(feats + (size_t)ids2[base + kk] * IN))[lane];
        s.x += v.x; s.y += v.y; s.z += v.z; s.w += v.w;
    }
    const bf16x4 a0 = {(__bf16)vx.x, (__bf16)vx.y, (__bf16)vx.z, (__bf16)vx.w};
    const bf16x4 a1 = {(__bf16)(s.x * 0.1f), (__bf16)(s.y * 0.1f),
                       (__bf16)(s.z * 0.1f), (__bf16)(s.w * 0.1f)};
    *(bf16x4*)&A0[(size_t)r * IN + lane * 4] = a0;
    *(bf16x4*)&A1[(size_t)r * IN + lane * 4] = a1;
}

// ---------------- Kernel M: h1 via MFMA, LDS-staged A, B-in-registers -------
// Grid 400 = 200 strips (64 rows) x 2 branches. 512 thr = 8 waves; wave w owns
// 16-col group. A-strip staged once (32KB LDS, XOR swizzle); B frags (16 x
// bf16x8 = 64 VGPR) loaded once per wave; 4 row-tiles of 16.
__global__ __launch_bounds__(512) void k_gemm(
    const __bf16* __restrict__ A0, const __bf16* __restrict__ A1,
    const __bf16* __restrict__ WtH, const __bf16* __restrict__ WtL,
    const float* __restrict__ bx, const float* __restrict__ bn,
    __bf16* __restrict__ h1)
{
    __shared__ __bf16 As[64 * IN];   // 32 KB
    const int tid   = threadIdx.x;
    const int strip = blockIdx.x >> 1;
    const int br    = blockIdx.x & 1;
    const int r0    = strip * 64;
    const __bf16* __restrict__ Ap = br ? A1 : A0;

    // ---- stage 64 rows x 256 k (contiguous, coalesced 16B/thread x 4)
    #pragma unroll
    for (int i = 0; i < 4; ++i) {
        const int idx = (i * 512 + tid) * 8;          // elem index, 8-aligned
        const bf16x8 v = *(const bf16x8*)&Ap[(size_t)r0 * IN + idx];
        const int row = idx >> 8;
        const int es  = idx ^ ((row & 7) << 3);       // 16B-slot XOR swizzle
        *(bf16x8*)&As[es] = v;
    }
    __syncthreads();

    const int lane = tid & 63;
    const int w    = tid >> 6;           // 0..7 -> 16-col group
    const int l15  = lane & 15;
    const int lk   = lane >> 4;
    const int colL = w * 16 + l15;       // 0..127 within branch
    const int colG = br * HIDC + colL;   // 0..255 global
    const float bv = (br ? bn : bx)[colL];

    // ---- load B fragments once (col = colG, all 8 k-blocks, hi+lo)
    bf16x8 bh[8], bl[8];
    #pragma unroll
    for (int kb = 0; kb < 8; ++kb) {
        const size_t eb = (size_t)colG * IN + kb * 32 + lk * 8;
        bh[kb] = *(const bf16x8*)&WtH[eb];
        bl[kb] = *(const bf16x8*)&WtL[eb];
    }

    // ---- 4 row-tiles of 16, A from LDS
    #pragma unroll
    for (int t = 0; t < 4; ++t) {
        const int rloc = t * 16 + l15;
        bf16x8 a[8];
        #pragma unroll
        for (int kb = 0; kb < 8; ++kb) {
            int ea = (rloc << 8) + kb * 32 + lk * 8;
            ea ^= (l15 & 7) << 3;                     // (rloc&7) == (l15&7)
            a[kb] = *(const bf16x8*)&As[ea];
        }
        f32x4 acc = {0.f, 0.f, 0.f, 0.f};
        #pragma unroll
        for (int kb = 0; kb < 8; ++kb) {
            acc = __builtin_amdgcn_mfma_f32_16x16x32_bf16(a[kb], bh[kb], acc, 0, 0, 0);
            acc = __builtin_amdgcn_mfma_f32_16x16x32_bf16(a[kb], bl[kb], acc, 0, 0, 0);
        }
        // C/D: col=lane&15 (-> colG), row=(lane>>4)*4+reg
        #pragma unroll
        for (int q = 0; q < 4; ++q) {
            h1[(size_t)(r0 + t * 16 + lk * 4 + q) * IN + colG] =
                (__bf16)fmaxf(acc[q] + bv, 0.f);
        }
    }
}

// ---------------- Kernel C: per output row, 512 threads ---------------------
__global__ __launch_bounds__(512) void k_out(
    const int* __restrict__ ids, const int* __restrict__ ids1,
    const float* __restrict__ feats,
    const __bf16* __restrict__ A0, const __bf16* __restrict__ h1,
    const float* __restrict__ Wx1, const float* __restrict__ bx1,
    const float* __restrict__ Wn1, const float* __restrict__ bn1,
    const float* __restrict__ Wx2, const float* __restrict__ bx2,
    const float* __restrict__ Wn2, const float* __restrict__ bn2,
    const float* __restrict__ Wfc, const float* __restrict__ bfc,
    float* __restrict__ out)
{
    __shared__ float x0[IN];
    __shared__ float m1[IN];
    __shared__ float mh[IN];
    __shared__ float h0[IN];
    __shared__ float g0[IN];
    __shared__ float partA[2][IN];
    __shared__ float partB[2][IN];
    __shared__ float red[8];
    __shared__ float fcred[7][4];
    const int i   = blockIdx.x;
    const int tid = threadIdx.x;
    const int c   = tid & 255;
    const int h   = tid >> 8;

    {
        float v1[13], v2[13];
        #pragma unroll
        for (int t = 0; t < 13; ++t) {
            const int kk = h * 13 + t;
            const int kc = kk < 25 ? kk : 24;
            const int r  = i * 25 + kc;
            v1[t] = (float)A0[(size_t)r * IN + c];
            v2[t] = (float)h1[(size_t)r * IN + c];
        }
        float s = 0.f, sh = 0.f;
        #pragma unroll
        for (int t = 0; t < 13; ++t) {
            const float msk = (h * 13 + t < 25) ? 1.f : 0.f;
            s  += msk * v1[t];
            sh += msk * v2[t];
        }
        if (h == 0) x0[c] = feats[(size_t)ids[i] * IN + c];
        partA[h][c] = s;
        partB[h][c] = sh;
    }
    __syncthreads();
    if (h == 0) m1[c] = (partA[0][c] + partA[1][c]) * 0.04f;
    else        mh[c] = (partB[0][c] + partB[1][c]) * 0.04f;
    __syncthreads();

    const int  jj = c & 127;
    const bool nb = (c >= 128);
    {
        const float* __restrict__ W = nb ? Wn1 : Wx1;
        const float* __restrict__ X = nb ? m1 : x0;
        float acc = 0.f;
        #pragma unroll 8
        for (int k = h * 128; k < h * 128 + 128; ++k)
            acc = fmaf(X[k], W[(size_t)k * HIDC + jj], acc);
        partA[h][c] = acc;
    }
    __syncthreads();
    if (h == 0)
        h0[c] = fmaxf(partA[0][c] + partA[1][c] + (nb ? bn1 : bx1)[jj], 0.f);
    __syncthreads();
    {
        const float* __restrict__ W = nb ? Wn2 : Wx2;
        const float* __restrict__ X = nb ? mh : h0;
        float acc = 0.f;
        #pragma unroll 8
        for (int k = h * 128; k < h * 128 + 128; ++k)
            acc = fmaf(X[k], W[(size_t)k * HIDC + jj], acc);
        partB[h][c] = acc;
    }
    __syncthreads();
    if (h == 0)
        g0[c] = partB[0][c] + partB[1][c] + (nb ? bn2 : bx2)[jj];
    __syncthreads();

    {
        const float gv = g0[c];
        float sq = gv * gv;
        #pragma unroll
        for (int off = 32; off > 0; off >>= 1) sq += __shfl_down(sq, off);
        if ((tid & 63) == 0) red[tid >> 6] = sq;
    }
    __syncthreads();
    const float total = (red[0] + red[1] + red[2] + red[3] +
                         red[4] + red[5] + red[6] + red[7]) * 0.5f;
    const float inv = 1.f / fmaxf(sqrtf(total), 1e-12f);
    const float p = g0[c] * inv;

    const int qbase = h * 4;
    const int qn    = h ? 3 : 4;
    for (int q = qbase; q < qbase + qn; ++q) {
        float t = p * Wfc[(size_t)c * 7 + q];
        #pragma unroll
        for (int off = 32; off > 0; off >>= 1) t += __shfl_down(t, off);
        if ((tid & 63) == 0) fcred[q][(tid >> 6) & 3] = t;
    }
    __syncthreads();
    if (tid < 7) {
        out[(size_t)i * 7 + tid] =
            fcred[tid][0] + fcred[tid][1] + fcred[tid][2] + fcred[tid][3] + bfc[tid];
    }
}

extern "C" void kernel_launch(void* const* d_in, const int* in_sizes, int n_in,
                              void* d_out, int out_size, void* d_ws, size_t ws_size,
                              hipStream_t stream) {
    const int*   ids   = (const int*)d_in[0];
    const int*   ids1  = (const int*)d_in[1];
    const int*   ids2  = (const int*)d_in[2];
    const float* feats = (const float*)d_in[3];
    const float* Wx1   = (const float*)d_in[4];
    const float* bx1   = (const float*)d_in[5];
    const float* Wn1   = (const float*)d_in[6];
    const float* bn1   = (const float*)d_in[7];
    const float* Wx2   = (const float*)d_in[8];
    const float* bx2   = (const float*)d_in[9];
    const float* Wn2   = (const float*)d_in[10];
    const float* bn2   = (const float*)d_in[11];
    const float* Wfc   = (const float*)d_in[12];
    const float* bfc   = (const float*)d_in[13];
    float* out = (float*)d_out;

    __bf16* A0  = (__bf16*)d_ws;                      // [12800][256] bf16
    __bf16* A1  = A0  + (size_t)ROWS1 * IN;           // [12800][256] bf16
    __bf16* h1  = A1  + (size_t)ROWS1 * IN;           // [12800][256] bf16
    __bf16* WtH = h1  + (size_t)ROWS1 * IN;           // [256][256] bf16
    __bf16* WtL = WtH + (size_t)IN * IN;

    k_wprep<<<256, 256, 0, stream>>>(Wx1, Wn1, WtH, WtL);
    k_gath<<<ROWS1 / 8, 512, 0, stream>>>(ids1, ids2, feats, A0, A1);
    // Launched twice on purpose (idempotent): timing probe to attribute
    // gather-vs-gemm cost via the round-over-round delta.
    k_gemm<<<400, 512, 0, stream>>>(A0, A1, WtH, WtL, bx1, bn1, h1);
    k_gemm<<<400, 512, 0, stream>>>(A0, A1, WtH, WtL, bx1, bn1, h1);
    k_out<<<512, 512, 0, stream>>>(ids, ids1, feats, A0, h1,
                                   Wx1, bx1, Wn1, bn1,
                                   Wx2, bx2, Wn2, bn2,
                                   Wfc, bfc, out);
}

// Round 13
// 61.249 us; speedup vs baseline: 1.1814x; 1.1814x over previous
//
#include <hip/hip_runtime.h>
#include <hip/hip_bf16.h>

// GraphSAGE 2-layer forward, SPLIT topology (round-12 minus the duplicate
// k_gemm launch -- probe: R12 - R13 = x (+launch delta) isolates the
// LDS-staged GEMM's true cost; every kernel byte-identical to round 12).
//   k_wprep: Wt = [Wx1|Wn1] cols, bf16 hi/lo
//   k_gath:  one wave per sample row: gather f1 + mean10(f2) -> A0/A1 bf16
//   k_gemm:  h1 = relu([A0@Wx1 ; A1@Wn1] + b); block = 64-row strip x branch;
//            A staged ONCE in LDS (32KB, XOR swizzle); W frags in registers.
//   k_out:   per output row: h0, g0, normalize, FC

typedef __bf16 bf16x8 __attribute__((ext_vector_type(8)));
typedef __bf16 bf16x4 __attribute__((ext_vector_type(4)));
typedef float  f32x4  __attribute__((ext_vector_type(4)));

constexpr int IN    = 256;
constexpr int HIDC  = 128;
constexpr int ROWS1 = 512 * 25;   // 12800

// ---------------- Kernel P0: Wt = [Wx1|Wn1] columns as bf16 hi/lo -----------
__global__ __launch_bounds__(256) void k_wprep(
    const float* __restrict__ Wx, const float* __restrict__ Wn,
    __bf16* __restrict__ WtH, __bf16* __restrict__ WtL)
{
    const int j = blockIdx.x;
    const int k = threadIdx.x;
    const float v = (j < HIDC) ? Wx[(size_t)k * HIDC + j]
                               : Wn[(size_t)k * HIDC + (j - HIDC)];
    const __bf16 h = (__bf16)v;
    const __bf16 l = (__bf16)(v - (float)h);
    const size_t o = (size_t)j * IN + k;
    WtH[o] = h;
    WtL[o] = l;
}

// ---------------- Kernel G: gather f1 + mean10(f2) -> bf16 panels -----------
__global__ __launch_bounds__(512) void k_gath(
    const int* __restrict__ ids1, const int* __restrict__ ids2,
    const float* __restrict__ feats,
    __bf16* __restrict__ A0, __bf16* __restrict__ A1)
{
    const int r    = blockIdx.x * 8 + (threadIdx.x >> 6);
    const int lane = threadIdx.x & 63;
    const int base = r * 10;

    const float4 vx = ((const float4*)(feats + (size_t)ids1[r] * IN))[lane];
    float4 s = make_float4(0.f, 0.f, 0.f, 0.f);
    #pragma unroll
    for (int kk = 0; kk < 10; ++kk) {
        const float4 v = ((const float4*)(feats + (size_t)ids2[base + kk] * IN))[lane];
        s.x += v.x; s.y += v.y; s.z += v.z; s.w += v.w;
    }
    const bf16x4 a0 = {(__bf16)vx.x, (__bf16)vx.y, (__bf16)vx.z, (__bf16)vx.w};
    const bf16x4 a1 = {(__bf16)(s.x * 0.1f), (__bf16)(s.y * 0.1f),
                       (__bf16)(s.z * 0.1f), (__bf16)(s.w * 0.1f)};
    *(bf16x4*)&A0[(size_t)r * IN + lane * 4] = a0;
    *(bf16x4*)&A1[(size_t)r * IN + lane * 4] = a1;
}

// ---------------- Kernel M: h1 via MFMA, LDS-staged A, B-in-registers -------
__global__ __launch_bounds__(512) void k_gemm(
    const __bf16* __restrict__ A0, const __bf16* __restrict__ A1,
    const __bf16* __restrict__ WtH, const __bf16* __restrict__ WtL,
    const float* __restrict__ bx, const float* __restrict__ bn,
    __bf16* __restrict__ h1)
{
    __shared__ __bf16 As[64 * IN];   // 32 KB
    const int tid   = threadIdx.x;
    const int strip = blockIdx.x >> 1;
    const int br    = blockIdx.x & 1;
    const int r0    = strip * 64;
    const __bf16* __restrict__ Ap = br ? A1 : A0;

    #pragma unroll
    for (int i = 0; i < 4; ++i) {
        const int idx = (i * 512 + tid) * 8;          // elem index, 8-aligned
        const bf16x8 v = *(const bf16x8*)&Ap[(size_t)r0 * IN + idx];
        const int row = idx >> 8;
        const int es  = idx ^ ((row & 7) << 3);       // 16B-slot XOR swizzle
        *(bf16x8*)&As[es] = v;
    }
    __syncthreads();

    const int lane = tid & 63;
    const int w    = tid >> 6;           // 0..7 -> 16-col group
    const int l15  = lane & 15;
    const int lk   = lane >> 4;
    const int colL = w * 16 + l15;       // 0..127 within branch
    const int colG = br * HIDC + colL;   // 0..255 global
    const float bv = (br ? bn : bx)[colL];

    bf16x8 bh[8], bl[8];
    #pragma unroll
    for (int kb = 0; kb < 8; ++kb) {
        const size_t eb = (size_t)colG * IN + kb * 32 + lk * 8;
        bh[kb] = *(const bf16x8*)&WtH[eb];
        bl[kb] = *(const bf16x8*)&WtL[eb];
    }

    #pragma unroll
    for (int t = 0; t < 4; ++t) {
        const int rloc = t * 16 + l15;
        bf16x8 a[8];
        #pragma unroll
        for (int kb = 0; kb < 8; ++kb) {
            int ea = (rloc << 8) + kb * 32 + lk * 8;
            ea ^= (l15 & 7) << 3;                     // (rloc&7) == (l15&7)
            a[kb] = *(const bf16x8*)&As[ea];
        }
        f32x4 acc = {0.f, 0.f, 0.f, 0.f};
        #pragma unroll
        for (int kb = 0; kb < 8; ++kb) {
            acc = __builtin_amdgcn_mfma_f32_16x16x32_bf16(a[kb], bh[kb], acc, 0, 0, 0);
            acc = __builtin_amdgcn_mfma_f32_16x16x32_bf16(a[kb], bl[kb], acc, 0, 0, 0);
        }
        #pragma unroll
        for (int q = 0; q < 4; ++q) {
            h1[(size_t)(r0 + t * 16 + lk * 4 + q) * IN + colG] =
                (__bf16)fmaxf(acc[q] + bv, 0.f);
        }
    }
}

// ---------------- Kernel C: per output row, 512 threads ---------------------
__global__ __launch_bounds__(512) void k_out(
    const int* __restrict__ ids, const int* __restrict__ ids1,
    const float* __restrict__ feats,
    const __bf16* __restrict__ A0, const __bf16* __restrict__ h1,
    const float* __restrict__ Wx1, const float* __restrict__ bx1,
    const float* __restrict__ Wn1, const float* __restrict__ bn1,
    const float* __restrict__ Wx2, const float* __restrict__ bx2,
    const float* __restrict__ Wn2, const float* __restrict__ bn2,
    const float* __restrict__ Wfc, const float* __restrict__ bfc,
    float* __restrict__ out)
{
    __shared__ float x0[IN];
    __shared__ float m1[IN];
    __shared__ float mh[IN];
    __shared__ float h0[IN];
    __shared__ float g0[IN];
    __shared__ float partA[2][IN];
    __shared__ float partB[2][IN];
    __shared__ float red[8];
    __shared__ float fcred[7][4];
    const int i   = blockIdx.x;
    const int tid = threadIdx.x;
    const int c   = tid & 255;
    const int h   = tid >> 8;

    {
        float v1[13], v2[13];
        #pragma unroll
        for (int t = 0; t < 13; ++t) {
            const int kk = h * 13 + t;
            const int kc = kk < 25 ? kk : 24;
            const int r  = i * 25 + kc;
            v1[t] = (float)A0[(size_t)r * IN + c];
            v2[t] = (float)h1[(size_t)r * IN + c];
        }
        float s = 0.f, sh = 0.f;
        #pragma unroll
        for (int t = 0; t < 13; ++t) {
            const float msk = (h * 13 + t < 25) ? 1.f : 0.f;
            s  += msk * v1[t];
            sh += msk * v2[t];
        }
        if (h == 0) x0[c] = feats[(size_t)ids[i] * IN + c];
        partA[h][c] = s;
        partB[h][c] = sh;
    }
    __syncthreads();
    if (h == 0) m1[c] = (partA[0][c] + partA[1][c]) * 0.04f;
    else        mh[c] = (partB[0][c] + partB[1][c]) * 0.04f;
    __syncthreads();

    const int  jj = c & 127;
    const bool nb = (c >= 128);
    {
        const float* __restrict__ W = nb ? Wn1 : Wx1;
        const float* __restrict__ X = nb ? m1 : x0;
        float acc = 0.f;
        #pragma unroll 8
        for (int k = h * 128; k < h * 128 + 128; ++k)
            acc = fmaf(X[k], W[(size_t)k * HIDC + jj], acc);
        partA[h][c] = acc;
    }
    __syncthreads();
    if (h == 0)
        h0[c] = fmaxf(partA[0][c] + partA[1][c] + (nb ? bn1 : bx1)[jj], 0.f);
    __syncthreads();
    {
        const float* __restrict__ W = nb ? Wn2 : Wx2;
        const float* __restrict__ X = nb ? mh : h0;
        float acc = 0.f;
        #pragma unroll 8
        for (int k = h * 128; k < h * 128 + 128; ++k)
            acc = fmaf(X[k], W[(size_t)k * HIDC + jj], acc);
        partB[h][c] = acc;
    }
    __syncthreads();
    if (h == 0)
        g0[c] = partB[0][c] + partB[1][c] + (nb ? bn2 : bx2)[jj];
    __syncthreads();

    {
        const float gv = g0[c];
        float sq = gv * gv;
        #pragma unroll
        for (int off = 32; off > 0; off >>= 1) sq += __shfl_down(sq, off);
        if ((tid & 63) == 0) red[tid >> 6] = sq;
    }
    __syncthreads();
    const float total = (red[0] + red[1] + red[2] + red[3] +
                         red[4] + red[5] + red[6] + red[7]) * 0.5f;
    const float inv = 1.f / fmaxf(sqrtf(total), 1e-12f);
    const float p = g0[c] * inv;

    const int qbase = h * 4;
    const int qn    = h ? 3 : 4;
    for (int q = qbase; q < qbase + qn; ++q) {
        float t = p * Wfc[(size_t)c * 7 + q];
        #pragma unroll
        for (int off = 32; off > 0; off >>= 1) t += __shfl_down(t, off);
        if ((tid & 63) == 0) fcred[q][(tid >> 6) & 3] = t;
    }
    __syncthreads();
    if (tid < 7) {
        out[(size_t)i * 7 + tid] =
            fcred[tid][0] + fcred[tid][1] + fcred[tid][2] + fcred[tid][3] + bfc[tid];
    }
}

extern "C" void kernel_launch(void* const* d_in, const int* in_sizes, int n_in,
                              void* d_out, int out_size, void* d_ws, size_t ws_size,
                              hipStream_t stream) {
    const int*   ids   = (const int*)d_in[0];
    const int*   ids1  = (const int*)d_in[1];
    const int*   ids2  = (const int*)d_in[2];
    const float* feats = (const float*)d_in[3];
    const float* Wx1   = (const float*)d_in[4];
    const float* bx1   = (const float*)d_in[5];
    const float* Wn1   = (const float*)d_in[6];
    const float* bn1   = (const float*)d_in[7];
    const float* Wx2   = (const float*)d_in[8];
    const float* bx2   = (const float*)d_in[9];
    const float* Wn2   = (const float*)d_in[10];
    const float* bn2   = (const float*)d_in[11];
    const float* Wfc   = (const float*)d_in[12];
    const float* bfc   = (const float*)d_in[13];
    float* out = (float*)d_out;

    __bf16* A0  = (__bf16*)d_ws;                      // [12800][256] bf16
    __bf16* A1  = A0  + (size_t)ROWS1 * IN;           // [12800][256] bf16
    __bf16* h1  = A1  + (size_t)ROWS1 * IN;           // [12800][256] bf16
    __bf16* WtH = h1  + (size_t)ROWS1 * IN;           // [256][256] bf16
    __bf16* WtL = WtH + (size_t)IN * IN;

    k_wprep<<<256, 256, 0, stream>>>(Wx1, Wn1, WtH, WtL);
    k_gath<<<ROWS1 / 8, 512, 0, stream>>>(ids1, ids2, feats, A0, A1);
    k_gemm<<<400, 512, 0, stream>>>(A0, A1, WtH, WtL, bx1, bn1, h1);
    k_out<<<512, 512, 0, stream>>>(ids, ids1, feats, A0, h1,
                                   Wx1, bx1, Wn1, bn1,
                                   Wx2, bx2, Wn2, bn2,
                                   Wfc, bfc, out);
}